// Round 2
// baseline (199.415 us; speedup 1.0000x reference)
//
#include <hip/hip_runtime.h>
#include <hip/hip_bf16.h>

// AdaBiD R8: SINGLE fused kernel. MI355X gfx950.
// B=8, T=12, N=1536, H=64, TH=768, HID2=128, T_OUT=12.
// 768 blocks x 256 threads, 3 blocks/CU guaranteed (47KB LDS, lb(256,3)).
// Phase A: block bi preps its OWN 16 rows (tid<16), a 33-item slice of the
//          weight repack (tid 64..96), and a slice of small params (tid 128..135,
//          bi<128). x goes straight into LDS xs (xT dropped).
// -- one device-scope grid barrier (manual, ws counters zeroed by memset) --
// Phase B: KL + bidirectional aggregation for the block's 16 i-rows; the 4
//          waves split j (384 each, 12 paired 32-wide tiles). Per-wave accF/accB
//          reduce through LDS into sfs/sbs: psf/psb global roundtrip ELIMINATED.
// Phase C: fused 6-layer MLP on the tile (identical to R7 fused_mlp body).

namespace {

constexpr int Nn = 1536, TOUT = 12;

typedef __attribute__((ext_vector_type(8))) short bf8;
typedef __attribute__((ext_vector_type(4))) float f4;
typedef unsigned short ush;

__device__ __forceinline__ float b2f(__hip_bfloat16 v) { return __bfloat162float(v); }
__device__ __forceinline__ ush f2bu(float f) {
  union { __hip_bfloat16 h; ush u; } c; c.h = __float2bfloat16(f); return c.u;
}
__device__ __forceinline__ float bu2f(ush u) {
  union { unsigned int i; float f; } c; c.i = ((unsigned)u) << 16; return c.f;
}
__device__ __forceinline__ float ldraw(const void* p, size_t i, int fl) {
  return fl ? ((const float*)p)[i] : b2f(((const __hip_bfloat16*)p)[i]);
}

// block-local dtype sniff: bf16 N(0,1) never has exp-field >= 140; f32 read
// as ushorts has ~45% of low-halves >= 140.  4096 samples.
__device__ __forceinline__ int detect_fl(const void* x, int tid) {
  __shared__ int cnt;
  if (tid == 0) cnt = 0;
  __syncthreads();
  const ush* u = (const ush*)x;
  int c = 0;
#pragma unroll
  for (int s = 0; s < 16; ++s) {
    ush v = u[tid + s * 256];
    if (((v >> 7) & 0xFF) >= 140) c++;
  }
  atomicAdd(&cnt, c);
  __syncthreads();
  return (cnt > 64) ? 1 : 0;
}

struct SmallTab { const void* src[16]; int n[16]; int off[16]; };
struct RepTab { const void* src[8]; int Nc[8]; int NCT[8]; int lb[9]; };

__global__ __launch_bounds__(256, 3) void mega(
    const void* __restrict__ xraw, SmallTab st, RepTab rt,
    int* __restrict__ bar, float* __restrict__ CS,
    float* __restrict__ sd,
    ush* __restrict__ pA, ush* __restrict__ lA,
    ush* __restrict__ phi16, ush* __restrict__ plo16,
    ush* __restrict__ lhi16, ush* __restrict__ llo16,
    ush* __restrict__ Xc, ush* __restrict__ Wf,
    void* __restrict__ outp) {
  __shared__ float xs[16][12], ccs[16][12];
  __shared__ float sfs[16][16], sbs[16][16];
  __shared__ float ws1[64], ws2[64];
  __shared__ ush hf[2048], hg[2048], xf[1024];
  __shared__ f4 red[4][64], red2[4][64];
  __shared__ union { ush T[2][4][512]; ush zf[12288]; } u;   // 24 KB alias

  int tid = threadIdx.x, w = tid >> 6, l = tid & 63, q = l >> 4, n = l & 15;
  int bi = blockIdx.x;
  int fl = detect_fl(xraw, tid);
  int r0 = bi * 16;
  int b = bi / 96;            // 96 blocks per batch (1536/16)
  int rowb = b * Nn;

  // ================= Phase A: prep / repack / smalls ========================
  if (tid < 16) {
    // ---- prep: one thread per row of the block's own 16-row tile ----
    int r = r0 + tid, nn = r - rowb;
    float xv[12];
#pragma unroll
    for (int t = 0; t < 12; ++t)
      xv[t] = ldraw(xraw, (size_t)(b * 12 + t) * Nn + nn, fl);
    float mx = xv[0];
#pragma unroll
    for (int t = 1; t < 12; ++t) mx = fmaxf(mx, xv[t]);
    float e[12], Z = 0.f;
#pragma unroll
    for (int t = 0; t < 12; ++t) { e[t] = expf(xv[t] - mx); Z += e[t]; }
    float invZ = 1.f / Z;
    float sacc = 0.f;
    ush pa[32], la[32], ph[16], pl[16], lh[16], ll[16];
#pragma unroll
    for (int k = 0; k < 32; ++k) { pa[k] = 0; la[k] = 0; }
#pragma unroll
    for (int k = 0; k < 16; ++k) { ph[k] = 0; pl[k] = 0; lh[k] = 0; ll[k] = 0; }
#pragma unroll
    for (int t = 0; t < 12; ++t) {
      float pv = e[t] * invZ;
      float lv = logf(pv + 1e-10f);
      sacc += pv * lv;
      xs[tid][t] = xv[t];
      ush phv = f2bu(pv);  float plv = pv - bu2f(phv);
      ush lhv = f2bu(lv);  float llv = lv - bu2f(lhv);
      pa[t] = phv; pa[16 + t] = f2bu(plv);
      la[t] = lhv; la[16 + t] = f2bu(llv);
      ph[t] = phv; pl[t] = f2bu(plv);
      lh[t] = lhv; ll[t] = f2bu(llv);
      Xc[((size_t)(b * 16 + t)) * Nn + nn] = f2bu(xv[t]);
    }
    Xc[((size_t)(b * 16 + 12)) * Nn + nn] = 0x3F80;  // ones col -> degrees
#pragma unroll
    for (int t = 13; t < 16; ++t) Xc[((size_t)(b * 16 + t)) * Nn + nn] = 0;
    sd[r] = sacc;
    {
      uint4* d = (uint4*)(pA + (size_t)r * 32);
      const uint4* s = (const uint4*)pa;
      d[0] = s[0]; d[1] = s[1]; d[2] = s[2]; d[3] = s[3];
      uint4* d2 = (uint4*)(lA + (size_t)r * 32);
      const uint4* s2 = (const uint4*)la;
      d2[0] = s2[0]; d2[1] = s2[1]; d2[2] = s2[2]; d2[3] = s2[3];
      ((uint4*)(phi16 + (size_t)r * 16))[0] = ((const uint4*)ph)[0];
      ((uint4*)(phi16 + (size_t)r * 16))[1] = ((const uint4*)ph)[1];
      ((uint4*)(plo16 + (size_t)r * 16))[0] = ((const uint4*)pl)[0];
      ((uint4*)(plo16 + (size_t)r * 16))[1] = ((const uint4*)pl)[1];
      ((uint4*)(lhi16 + (size_t)r * 16))[0] = ((const uint4*)lh)[0];
      ((uint4*)(lhi16 + (size_t)r * 16))[1] = ((const uint4*)lh)[1];
      ((uint4*)(llo16 + (size_t)r * 16))[0] = ((const uint4*)ll)[0];
      ((uint4*)(llo16 + (size_t)r * 16))[1] = ((const uint4*)ll)[1];
    }
  } else if (tid >= 64 && tid < 97) {
    // ---- repack: 33-item slice per block (24960 items total) ----
    int idx = bi * 33 + (tid - 64);
    if (idx < rt.lb[8]) {
      int mi = 0;
#pragma unroll
      for (int i = 1; i < 8; ++i) if (idx >= rt.lb[i]) mi = i;
      int li = idx - rt.lb[mi];
      int NCT = rt.NCT[mi], Nc = rt.Nc[mi];
      int per = NCT * 64;
      int c0 = li / per, rem = li - c0 * per;
      int ct = rem >> 6, lq = rem & 63;
      int qq = lq >> 4, m = lq & 15;
      int col = ct * 16 + m;
      ush* d = Wf + (size_t)idx * 8;
#pragma unroll
      for (int j = 0; j < 8; ++j) {
        int k = c0 * 32 + qq * 8 + j;
        d[j] = (col < Nc) ? f2bu(ldraw(rt.src[mi], (size_t)k * Nc + col, fl)) : 0;
      }
    }
  } else if (tid >= 128 && tid < 136 && bi < 128) {
    // ---- smalls: canonicalize biases/BN params to f32 (1020 elems) ----
    int e = bi * 8 + (tid - 128);
    if (e < 1020) {
      int i = 0;
#pragma unroll
      for (int k = 1; k < 16; ++k) if (e >= st.off[k]) i = k;
      CS[e] = ldraw(st.src[i], e - st.off[i], fl);
    }
  }

  // ================= grid barrier (all 768 blocks co-resident) ==============
  __syncthreads();
  if (tid == 0) {
    __threadfence();                       // release phase-A stores
    int arr = atomicAdd(bar, 1);
    if (arr == 767) {
      atomicExch(bar + 1, 1);
    } else {
      while (atomicAdd(bar + 1, 0) == 0) __builtin_amdgcn_s_sleep(8);
    }
    __threadfence();                       // acquire other blocks' stores
  }
  __syncthreads();

  // ================= Phase B: KL + aggregation, 4 waves split j =============
  {
    bf8 z8 = {0, 0, 0, 0, 0, 0, 0, 0};
    bf8 aP = *(const bf8*)(pA + ((size_t)(r0 + n)) * 32 + q * 8);
    bf8 aL = *(const bf8*)(lA + ((size_t)(r0 + n)) * 32 + q * 8);
    bf8 aPh = (q < 2) ? aP : z8;
    bf8 aLh = (q < 2) ? aL : z8;
    float selfI[4];
#pragma unroll
    for (int r = 0; r < 4; ++r) selfI[r] = sd[r0 + q * 4 + r];

    f4 accF = {0.f, 0.f, 0.f, 0.f}, accB = {0.f, 0.f, 0.f, 0.f};

    for (int jp = 0; jp < 12; ++jp) {
      int jl = w * 384 + jp * 32;
#pragma unroll
      for (int hh = 0; hh < 2; ++hh) {
        int jh = jl + hh * 16;
        size_t bb = ((size_t)(rowb + jh + n)) * 16 + (q & 1) * 8;
        bf8 bLh = *(const bf8*)(lhi16 + bb);
        bf8 bLo = *(const bf8*)(llo16 + bb);
        bf8 bPh = *(const bf8*)(phi16 + bb);
        bf8 bPo = *(const bf8*)(plo16 + bb);
        float selfJ = sd[rowb + jh + n];

        f4 s1 = {0.f, 0.f, 0.f, 0.f}, s2 = {0.f, 0.f, 0.f, 0.f};
        s1 = __builtin_amdgcn_mfma_f32_16x16x32_bf16(aP, bLh, s1, 0, 0, 0);
        s1 = __builtin_amdgcn_mfma_f32_16x16x32_bf16(aPh, bLo, s1, 0, 0, 0);
        s2 = __builtin_amdgcn_mfma_f32_16x16x32_bf16(aL, bPh, s2, 0, 0, 0);
        s2 = __builtin_amdgcn_mfma_f32_16x16x32_bf16(aLh, bPo, s2, 0, 0, 0);

        int qk = n >> 3, kj = n & 7;
#pragma unroll
        for (int r = 0; r < 4; ++r) {
          int pos = hh * 256 + (qk * 16 + q * 4 + r) * 8 + kj;
          u.T[0][w][pos] = (selfI[r] - s1[r] < 0.5f) ? (ush)0x3F80 : (ush)0;
          u.T[1][w][pos] = (selfJ - s2[r] < 0.5f) ? (ush)0x3F80 : (ush)0;
        }
      }
      bf8 af1 = *(const bf8*)(&u.T[0][w][(size_t)l * 8]);
      bf8 af2 = *(const bf8*)(&u.T[1][w][(size_t)l * 8]);
      bf8 xfr = *(const bf8*)(Xc + ((size_t)(b * 16 + n)) * Nn + jl + q * 8);
      accF = __builtin_amdgcn_mfma_f32_16x16x32_bf16(af1, xfr, accF, 0, 0, 0);
      accB = __builtin_amdgcn_mfma_f32_16x16x32_bf16(af2, xfr, accB, 0, 0, 0);
    }
    red[w][l] = accF;
    red2[w][l] = accB;
  }
  __syncthreads();

  // j-split reduction -> sfs/sbs; waves 2,3 stage W1/W2 meanwhile
  if (w == 0) {
    f4 s = red[0][l] + red[1][l] + red[2][l] + red[3][l];
#pragma unroll
    for (int r = 0; r < 4; ++r) sfs[q * 4 + r][n] = s[r];
  } else if (w == 1) {
    f4 s = red2[0][l] + red2[1][l] + red2[2][l] + red2[3][l];
#pragma unroll
    for (int r = 0; r < 4; ++r) sbs[q * 4 + r][n] = s[r];
  } else if (w == 2) {
    ws1[l] = CS[l];
  } else {
    ws2[l] = CS[64 + l];
  }
  __syncthreads();
  if (tid < 192) {
    int rr = tid / 12, tt = tid - rr * 12;
    float irs = 1.f / fmaxf(sfs[rr][12], 1e-6f);
    float ics = 1.f / fmaxf(sbs[rr][12], 1e-6f);
    ccs[rr][tt] = 3.0f * (0.3f * sfs[rr][tt] * irs + 0.7f * sbs[rr][tt] * ics);
  }
  __syncthreads();

  // ================= Phase C: fused MLP (R7 body) ===========================
  // z A-frag regen: row = r0+n, k = c0*32 + q*8 + j
  auto zregen = [&](int c0) -> bf8 {
    int t = c0 >> 1, h0 = (c0 & 1) * 32 + q * 8;
    float xv = xs[n][t], cv = ccs[n][t];
    union { bf8 v; ush uu[8]; } au;
#pragma unroll
    for (int j = 0; j < 8; ++j)
      au.uu[j] = f2bu(fmaxf(fmaf(xv, ws1[h0 + j], cv * ws2[h0 + j]), 0.f));
    return au.v;
  };
  auto fpos = [&](int ct, int r) -> int {
    return ((ct >> 1) * 64 + ((ct & 1) * 2 + (n >> 3)) * 16 + q * 4 + r) * 8 + (n & 7);
  };

  // fill the z-frag cache (aliases T; all T reads are done): wave w owns 6 c0s
#pragma unroll
  for (int u6 = 0; u6 < 6; ++u6) {
    int c0 = w * 6 + u6;
    bf8 v = zregen(c0);
    *(bf8*)(&u.zf[((size_t)c0 * 64 + l) * 8]) = v;
  }
  __syncthreads();

  // --- L1e: h1 = relu(z @ ew1 + b1), N=128, wave does ct = 2w, 2w+1 --------
  {
    f4 a0 = {0.f, 0.f, 0.f, 0.f}, a1 = {0.f, 0.f, 0.f, 0.f};
    for (int c0 = 0; c0 < 24; ++c0) {
      bf8 a = *(const bf8*)(&u.zf[((size_t)c0 * 64 + l) * 8]);
      const ush* wb = Wf + ((size_t)(c0 * 8 + 2 * w) * 64 + l) * 8;
      bf8 b0 = *(const bf8*)wb;
      bf8 b1 = *(const bf8*)(wb + 512);
      a0 = __builtin_amdgcn_mfma_f32_16x16x32_bf16(a, b0, a0, 0, 0, 0);
      a1 = __builtin_amdgcn_mfma_f32_16x16x32_bf16(a, b1, a1, 0, 0, 0);
    }
#pragma unroll
    for (int u2 = 0; u2 < 2; ++u2) {
      int ct = 2 * w + u2;
      f4 acc = u2 ? a1 : a0;
      float bz = CS[128 + ct * 16 + n];
#pragma unroll
      for (int r = 0; r < 4; ++r)
        hf[fpos(ct, r)] = f2bu(fmaxf(acc[r] + bz, 0.f));
    }
  }
  __syncthreads();

  // --- L2e: h2 = relu(h1 @ ew2 + b2), K=128 --------------------------------
  {
    f4 a0 = {0.f, 0.f, 0.f, 0.f}, a1 = {0.f, 0.f, 0.f, 0.f};
    for (int c0 = 0; c0 < 4; ++c0) {
      bf8 a = *(const bf8*)(&hf[(size_t)(c0 * 64 + l) * 8]);
      const ush* wb = Wf + 98304 + ((size_t)(c0 * 8 + 2 * w) * 64 + l) * 8;
      bf8 b0 = *(const bf8*)wb;
      bf8 b1 = *(const bf8*)(wb + 512);
      a0 = __builtin_amdgcn_mfma_f32_16x16x32_bf16(a, b0, a0, 0, 0, 0);
      a1 = __builtin_amdgcn_mfma_f32_16x16x32_bf16(a, b1, a1, 0, 0, 0);
    }
    __syncthreads();   // hf reads complete before any rewrite hazards
#pragma unroll
    for (int u2 = 0; u2 < 2; ++u2) {
      int ct = 2 * w + u2;
      f4 acc = u2 ? a1 : a0;
      float bz = CS[256 + ct * 16 + n];
#pragma unroll
      for (int r = 0; r < 4; ++r)
        hg[fpos(ct, r)] = f2bu(fmaxf(acc[r] + bz, 0.f));
    }
  }
  __syncthreads();

  // --- L3e: xe = BN(h2 @ ew3 + b3 + z @ eproj), N=64, wave does ct = w -----
  {
    f4 a3 = {0.f, 0.f, 0.f, 0.f};
    for (int c0 = 0; c0 < 4; ++c0) {
      bf8 a = *(const bf8*)(&hg[(size_t)(c0 * 64 + l) * 8]);
      bf8 bb = *(const bf8*)(Wf + 114688 + ((size_t)(c0 * 4 + w) * 64 + l) * 8);
      a3 = __builtin_amdgcn_mfma_f32_16x16x32_bf16(a, bb, a3, 0, 0, 0);
    }
    for (int c0 = 0; c0 < 24; ++c0) {
      bf8 a = *(const bf8*)(&u.zf[((size_t)c0 * 64 + l) * 8]);
      bf8 bb = *(const bf8*)(Wf + 122880 + ((size_t)(c0 * 4 + w) * 64 + l) * 8);
      a3 = __builtin_amdgcn_mfma_f32_16x16x32_bf16(a, bb, a3, 0, 0, 0);
    }
    int col = w * 16 + n;
    float g = CS[448 + col], be = CS[512 + col], mm = CS[576 + col], vv = CS[640 + col];
    float sc = g / sqrtf(vv + 1e-5f);
    float sh = be - mm * sc;
    float bz = CS[384 + col];
#pragma unroll
    for (int r = 0; r < 4; ++r)
      xf[fpos(w, r)] = f2bu((a3[r] + bz) * sc + sh);
  }
  __syncthreads();

  // --- L1d: g1 = relu(xe @ dw1 + b1), K=64, N=128 --------------------------
  {
    f4 a0 = {0.f, 0.f, 0.f, 0.f}, a1 = {0.f, 0.f, 0.f, 0.f};
    for (int c0 = 0; c0 < 2; ++c0) {
      bf8 a = *(const bf8*)(&xf[(size_t)(c0 * 64 + l) * 8]);
      const ush* wb = Wf + 172032 + ((size_t)(c0 * 8 + 2 * w) * 64 + l) * 8;
      bf8 b0 = *(const bf8*)wb;
      bf8 b1 = *(const bf8*)(wb + 512);
      a0 = __builtin_amdgcn_mfma_f32_16x16x32_bf16(a, b0, a0, 0, 0, 0);
      a1 = __builtin_amdgcn_mfma_f32_16x16x32_bf16(a, b1, a1, 0, 0, 0);
    }
    __syncthreads();   // hf rewrite fence
#pragma unroll
    for (int u2 = 0; u2 < 2; ++u2) {
      int ct = 2 * w + u2;
      f4 acc = u2 ? a1 : a0;
      float bz = CS[704 + ct * 16 + n];
#pragma unroll
      for (int r = 0; r < 4; ++r)
        hf[fpos(ct, r)] = f2bu(fmaxf(acc[r] + bz, 0.f));
    }
  }
  __syncthreads();

  // --- L2d: g2 = relu(g1 @ dw2 + b2), K=128 --------------------------------
  {
    f4 a0 = {0.f, 0.f, 0.f, 0.f}, a1 = {0.f, 0.f, 0.f, 0.f};
    for (int c0 = 0; c0 < 4; ++c0) {
      bf8 a = *(const bf8*)(&hf[(size_t)(c0 * 64 + l) * 8]);
      const ush* wb = Wf + 180224 + ((size_t)(c0 * 8 + 2 * w) * 64 + l) * 8;
      bf8 b0 = *(const bf8*)wb;
      bf8 b1 = *(const bf8*)(wb + 512);
      a0 = __builtin_amdgcn_mfma_f32_16x16x32_bf16(a, b0, a0, 0, 0, 0);
      a1 = __builtin_amdgcn_mfma_f32_16x16x32_bf16(a, b1, a1, 0, 0, 0);
    }
    __syncthreads();   // hg rewrite fence
#pragma unroll
    for (int u2 = 0; u2 < 2; ++u2) {
      int ct = 2 * w + u2;
      f4 acc = u2 ? a1 : a0;
      float bz = CS[832 + ct * 16 + n];
#pragma unroll
      for (int r = 0; r < 4; ++r)
        hg[fpos(ct, r)] = f2bu(fmaxf(acc[r] + bz, 0.f));
    }
  }
  __syncthreads();

  // --- L3d: out = BN(g2 @ dw3 + b3 + xe @ dproj), N=12; K-split 4 waves ----
  {
    f4 ao = {0.f, 0.f, 0.f, 0.f};
    {  // dw3 chunk c0 = w  (K=128 -> 4 chunks)
      bf8 a = *(const bf8*)(&hg[(size_t)(w * 64 + l) * 8]);
      bf8 bb = *(const bf8*)(Wf + 196608 + ((size_t)w * 64 + l) * 8);
      ao = __builtin_amdgcn_mfma_f32_16x16x32_bf16(a, bb, ao, 0, 0, 0);
    }
    if (w < 2) {  // dproj chunk c0 = w  (K=64 -> 2 chunks)
      bf8 a = *(const bf8*)(&xf[(size_t)(w * 64 + l) * 8]);
      bf8 bb = *(const bf8*)(Wf + 198656 + ((size_t)w * 64 + l) * 8);
      ao = __builtin_amdgcn_mfma_f32_16x16x32_bf16(a, bb, ao, 0, 0, 0);
    }
    red[w][l] = ao;
  }
  __syncthreads();
  if (w == 0) {
    f4 s = red[0][l] + red[1][l] + red[2][l] + red[3][l];
    if (n < 12) {
      float bz = CS[960 + n];
      float g = CS[972 + n], be = CS[984 + n], mm = CS[996 + n], vv = CS[1008 + n];
      float sc = g / sqrtf(vv + 1e-5f);
      float sh = be - mm * sc;
#pragma unroll
      for (int r = 0; r < 4; ++r) {
        int row = r0 + q * 4 + r;
        int bb2 = row / Nn, nn2 = row - bb2 * Nn;
        size_t oi = ((size_t)bb2 * TOUT + n) * Nn + nn2;
        float ov = (s[r] + bz) * sc + sh;
        if (fl) ((float*)outp)[oi] = ov;
        else    ((ush*)outp)[oi] = f2bu(ov);
      }
    }
  }
}

}  // namespace

extern "C" void kernel_launch(void* const* d_in, const int* in_sizes, int n_in,
                              void* d_out, int out_size, void* d_ws, size_t ws_size,
                              hipStream_t stream) {
  float* f = (float*)d_ws;
  int* bar   = (int*)d_ws;                // f[0..3]: barrier counter + sense
  float* CS  = f + 16;                    // 1020 small params (f32)
  float* sd  = f + 1040;                  // 12288
  ush* U = (ush*)(f + 13328);
  ush* pA    = U;                         // 12288*32
  ush* lA    = U + 393216;
  ush* phi16 = U + 786432;                // 12288*16
  ush* plo16 = U + 983040;
  ush* lhi16 = U + 1179648;
  ush* llo16 = U + 1376256;
  ush* Xc    = U + 1572864;               // 8*16*1536
  ush* Wf    = U + 1769472;               // 199680

  SmallTab st;
  {
    const int idxs[16] = {1, 2, 4, 6, 8, 10, 11, 12, 13, 15, 17, 19, 21, 22, 23, 24};
    const int ns[16]   = {64, 64, 128, 128, 64, 64, 64, 64, 64, 128, 128, 12, 12, 12, 12, 12};
    int off = 0;
    for (int i = 0; i < 16; ++i) {
      st.src[i] = d_in[idxs[i]]; st.n[i] = ns[i]; st.off[i] = off; off += ns[i];
    }
  }
  RepTab rt;
  {
    const int idxs[8]  = {3, 5, 7, 9, 14, 16, 18, 20};
    const int rNc[8]   = {128, 128, 64, 64, 128, 128, 12, 12};
    const int rNCT[8]  = {8, 8, 4, 4, 8, 8, 1, 1};
    const int rlb[9]   = {0, 12288, 14336, 15360, 21504, 22528, 24576, 24832, 24960};
    for (int i = 0; i < 8; ++i) {
      rt.src[i] = d_in[idxs[i]]; rt.Nc[i] = rNc[i]; rt.NCT[i] = rNCT[i];
    }
    for (int i = 0; i < 9; ++i) rt.lb[i] = rlb[i];
  }

  hipMemsetAsync(d_ws, 0, 16, stream);    // zero the grid-barrier words
  mega<<<768, 256, 0, stream>>>(d_in[0], st, rt, bar, CS, sd,
                                pA, lA, phi16, plo16, lhi16, llo16,
                                Xc, Wf, d_out);
}

// Round 3
// 142.449 us; speedup vs baseline: 1.3999x; 1.3999x over previous
//
#include <hip/hip_runtime.h>
#include <hip/hip_bf16.h>

// AdaBiD R9: 2-kernel pipeline. MI355X gfx950.
// B=8, T=12, N=1536, H=64, TH=768, HID2=128, T_OUT=12.
//  K1 prep_all (R7 K1 verbatim): [0,48) softmax/logp/self-dot + frag arrays,
//               [48,146) weight repack -> B-frag order, 146 smalls + flag.
//  K2 klmlp: fused KL + 6-layer MLP per 16-row tile (768 blocks).
//               Phase B: 4 waves split j (384 each, 12 paired 32-wide tiles),
//               per-wave accF/accB reduce through LDS into sfs/sbs --
//               psf/psb global roundtrip eliminated, NO grid barrier
//               (R8's atomic-spin barrier was the regression: 767 blocks
//               RMW-polling one line = serialization storm).
//               Phase C: 6-layer MLP with 24KB zf A-frag cache (aliases the
//               KL mask buffers). 47.6KB LDS -> 3 blocks/CU, one dispatch wave.

namespace {

constexpr int Nn = 1536, TOUT = 12;

typedef __attribute__((ext_vector_type(8))) short bf8;
typedef __attribute__((ext_vector_type(4))) float f4;
typedef unsigned short ush;

__device__ __forceinline__ float b2f(__hip_bfloat16 v) { return __bfloat162float(v); }
__device__ __forceinline__ ush f2bu(float f) {
  union { __hip_bfloat16 h; ush u; } c; c.h = __float2bfloat16(f); return c.u;
}
__device__ __forceinline__ float bu2f(ush u) {
  union { unsigned int i; float f; } c; c.i = ((unsigned)u) << 16; return c.f;
}
__device__ __forceinline__ float ldraw(const void* p, size_t i, int fl) {
  return fl ? ((const float*)p)[i] : b2f(((const __hip_bfloat16*)p)[i]);
}

// block-local dtype sniff: bf16 N(0,1) never has exp-field >= 140; f32 read
// as ushorts has ~45% of low-halves >= 140.  4096 samples.
__device__ __forceinline__ int detect_fl(const void* x, int tid) {
  __shared__ int cnt;
  if (tid == 0) cnt = 0;
  __syncthreads();
  const ush* u = (const ush*)x;
  int c = 0;
#pragma unroll
  for (int s = 0; s < 16; ++s) {
    ush v = u[tid + s * 256];
    if (((v >> 7) & 0xFF) >= 140) c++;
  }
  atomicAdd(&cnt, c);
  __syncthreads();
  return (cnt > 64) ? 1 : 0;
}

struct SmallTab { const void* src[16]; int n[16]; int off[16]; };
struct RepTab { const void* src[8]; int Nc[8]; int NCT[8]; int lb[9]; };

// ---------------- K1: prep + repack + smalls ---------------------------------
__global__ __launch_bounds__(256) void prep_all(
    const void* __restrict__ xraw, SmallTab st, RepTab rt,
    int* __restrict__ flag, float* __restrict__ CS,
    float* __restrict__ xT, float* __restrict__ sd,
    ush* __restrict__ pA, ush* __restrict__ lA,
    ush* __restrict__ phi16, ush* __restrict__ plo16,
    ush* __restrict__ lhi16, ush* __restrict__ llo16,
    ush* __restrict__ Xc, ush* __restrict__ Wf) {
  int tid = threadIdx.x;
  int fl = detect_fl(xraw, tid);
  int blk = blockIdx.x;

  if (blk < 48) {
    // ---- prep role: one thread per (b,n) row ----
    int row = blk * 256 + tid;
    int b = row / Nn, n = row - b * Nn;
    float xv[12];
#pragma unroll
    for (int t = 0; t < 12; ++t)
      xv[t] = ldraw(xraw, (size_t)(b * 12 + t) * Nn + n, fl);
    float mx = xv[0];
#pragma unroll
    for (int t = 1; t < 12; ++t) mx = fmaxf(mx, xv[t]);
    float e[12], Z = 0.f;
#pragma unroll
    for (int t = 0; t < 12; ++t) { e[t] = expf(xv[t] - mx); Z += e[t]; }
    float invZ = 1.f / Z;
    float sacc = 0.f;
    ush pa[32], la[32], ph[16], pl[16], lh[16], ll[16];
#pragma unroll
    for (int k = 0; k < 32; ++k) { pa[k] = 0; la[k] = 0; }
#pragma unroll
    for (int k = 0; k < 16; ++k) { ph[k] = 0; pl[k] = 0; lh[k] = 0; ll[k] = 0; }
#pragma unroll
    for (int t = 0; t < 12; ++t) {
      float pv = e[t] * invZ;
      float lv = logf(pv + 1e-10f);
      sacc += pv * lv;
      xT[(size_t)row * 12 + t] = xv[t];
      ush phv = f2bu(pv);  float plv = pv - bu2f(phv);
      ush lhv = f2bu(lv);  float llv = lv - bu2f(lhv);
      pa[t] = phv; pa[16 + t] = f2bu(plv);
      la[t] = lhv; la[16 + t] = f2bu(llv);
      ph[t] = phv; pl[t] = f2bu(plv);
      lh[t] = lhv; ll[t] = f2bu(llv);
      Xc[((size_t)(b * 16 + t)) * Nn + n] = f2bu(xv[t]);
    }
    Xc[((size_t)(b * 16 + 12)) * Nn + n] = 0x3F80;  // ones col -> degrees
#pragma unroll
    for (int t = 13; t < 16; ++t) Xc[((size_t)(b * 16 + t)) * Nn + n] = 0;
    sd[row] = sacc;
    {
      uint4* d = (uint4*)(pA + (size_t)row * 32);
      const uint4* s = (const uint4*)pa;
      d[0] = s[0]; d[1] = s[1]; d[2] = s[2]; d[3] = s[3];
      uint4* d2 = (uint4*)(lA + (size_t)row * 32);
      const uint4* s2 = (const uint4*)la;
      d2[0] = s2[0]; d2[1] = s2[1]; d2[2] = s2[2]; d2[3] = s2[3];
      ((uint4*)(phi16 + (size_t)row * 16))[0] = ((const uint4*)ph)[0];
      ((uint4*)(phi16 + (size_t)row * 16))[1] = ((const uint4*)ph)[1];
      ((uint4*)(plo16 + (size_t)row * 16))[0] = ((const uint4*)pl)[0];
      ((uint4*)(plo16 + (size_t)row * 16))[1] = ((const uint4*)pl)[1];
      ((uint4*)(lhi16 + (size_t)row * 16))[0] = ((const uint4*)lh)[0];
      ((uint4*)(lhi16 + (size_t)row * 16))[1] = ((const uint4*)lh)[1];
      ((uint4*)(llo16 + (size_t)row * 16))[0] = ((const uint4*)ll)[0];
      ((uint4*)(llo16 + (size_t)row * 16))[1] = ((const uint4*)ll)[1];
    }
  } else if (blk < 146) {
    // ---- repack role: weights -> MFMA B-frag order ----
    int idx = (blk - 48) * 256 + tid;
    if (idx >= rt.lb[8]) return;
    int mi = 0;
#pragma unroll
    for (int i = 1; i < 8; ++i) if (idx >= rt.lb[i]) mi = i;
    int li = idx - rt.lb[mi];
    int NCT = rt.NCT[mi], Nc = rt.Nc[mi];
    int per = NCT * 64;
    int c0 = li / per, rem = li - c0 * per;
    int ct = rem >> 6, l = rem & 63;
    int q = l >> 4, m = l & 15;
    int col = ct * 16 + m;
    ush* d = Wf + (size_t)idx * 8;
#pragma unroll
    for (int j = 0; j < 8; ++j) {
      int k = c0 * 32 + q * 8 + j;
      d[j] = (col < Nc) ? f2bu(ldraw(rt.src[mi], (size_t)k * Nc + col, fl)) : 0;
    }
  } else {
    // ---- smalls role: canonicalize biases/BN params to f32 + publish flag ----
    for (int i = 0; i < 16; ++i)
      for (int e = tid; e < st.n[i]; e += 256)
        CS[st.off[i] + e] = ldraw(st.src[i], e, fl);
    if (tid == 0) flag[0] = fl;
  }
}

// ---------------- K2: fused KL + MLP per 16-row tile -------------------------
__global__ __launch_bounds__(256, 3) void klmlp(
    const float* __restrict__ xT,
    const ush* __restrict__ pA, const ush* __restrict__ lA,
    const ush* __restrict__ phi16, const ush* __restrict__ plo16,
    const ush* __restrict__ lhi16, const ush* __restrict__ llo16,
    const ush* __restrict__ Xc, const float* __restrict__ sd,
    const float* __restrict__ CS, const ush* __restrict__ Wf,
    const int* __restrict__ flag, void* __restrict__ outp) {
  __shared__ float xs[16][12], ccs[16][12];
  __shared__ float sfs[16][16], sbs[16][16];
  __shared__ float ws1[64], ws2[64];
  __shared__ ush hf[2048], hg[2048], xf[1024];
  __shared__ f4 red[4][64], red2[4][64];
  __shared__ union { ush T[2][4][512]; ush zf[12288]; } u;   // 24 KB alias

  int tid = threadIdx.x, w = tid >> 6, l = tid & 63, q = l >> 4, n = l & 15;
  int bi = blockIdx.x;
  int r0 = bi * 16;
  int b = bi / 96;            // 96 blocks per batch (1536/16)
  int rowb = b * Nn;

  // xs staging overlaps phase B (independent loads)
  if (tid < 192) {
    int rr = tid / 12, tt = tid - rr * 12;
    xs[rr][tt] = xT[(size_t)(r0 + rr) * 12 + tt];
  }

  // ================= Phase B: KL + aggregation, 4 waves split j =============
  {
    bf8 z8 = {0, 0, 0, 0, 0, 0, 0, 0};
    bf8 aP = *(const bf8*)(pA + ((size_t)(r0 + n)) * 32 + q * 8);
    bf8 aL = *(const bf8*)(lA + ((size_t)(r0 + n)) * 32 + q * 8);
    bf8 aPh = (q < 2) ? aP : z8;
    bf8 aLh = (q < 2) ? aL : z8;
    float selfI[4];
#pragma unroll
    for (int r = 0; r < 4; ++r) selfI[r] = sd[r0 + q * 4 + r];

    f4 accF = {0.f, 0.f, 0.f, 0.f}, accB = {0.f, 0.f, 0.f, 0.f};

    for (int jp = 0; jp < 12; ++jp) {
      int jl = w * 384 + jp * 32;
#pragma unroll
      for (int hh = 0; hh < 2; ++hh) {
        int jh = jl + hh * 16;
        size_t bb = ((size_t)(rowb + jh + n)) * 16 + (q & 1) * 8;
        bf8 bLh = *(const bf8*)(lhi16 + bb);
        bf8 bLo = *(const bf8*)(llo16 + bb);
        bf8 bPh = *(const bf8*)(phi16 + bb);
        bf8 bPo = *(const bf8*)(plo16 + bb);
        float selfJ = sd[rowb + jh + n];

        f4 s1 = {0.f, 0.f, 0.f, 0.f}, s2 = {0.f, 0.f, 0.f, 0.f};
        s1 = __builtin_amdgcn_mfma_f32_16x16x32_bf16(aP, bLh, s1, 0, 0, 0);
        s1 = __builtin_amdgcn_mfma_f32_16x16x32_bf16(aPh, bLo, s1, 0, 0, 0);
        s2 = __builtin_amdgcn_mfma_f32_16x16x32_bf16(aL, bPh, s2, 0, 0, 0);
        s2 = __builtin_amdgcn_mfma_f32_16x16x32_bf16(aLh, bPo, s2, 0, 0, 0);

        int qk = n >> 3, kj = n & 7;
#pragma unroll
        for (int r = 0; r < 4; ++r) {
          int pos = hh * 256 + (qk * 16 + q * 4 + r) * 8 + kj;
          u.T[0][w][pos] = (selfI[r] - s1[r] < 0.5f) ? (ush)0x3F80 : (ush)0;
          u.T[1][w][pos] = (selfJ - s2[r] < 0.5f) ? (ush)0x3F80 : (ush)0;
        }
      }
      bf8 af1 = *(const bf8*)(&u.T[0][w][(size_t)l * 8]);
      bf8 af2 = *(const bf8*)(&u.T[1][w][(size_t)l * 8]);
      bf8 xfr = *(const bf8*)(Xc + ((size_t)(b * 16 + n)) * Nn + jl + q * 8);
      accF = __builtin_amdgcn_mfma_f32_16x16x32_bf16(af1, xfr, accF, 0, 0, 0);
      accB = __builtin_amdgcn_mfma_f32_16x16x32_bf16(af2, xfr, accB, 0, 0, 0);
    }
    red[w][l] = accF;
    red2[w][l] = accB;
  }
  __syncthreads();

  // j-split reduction -> sfs/sbs; waves 2,3 stage W1/W2 meanwhile
  if (w == 0) {
    f4 s = red[0][l] + red[1][l] + red[2][l] + red[3][l];
#pragma unroll
    for (int r = 0; r < 4; ++r) sfs[q * 4 + r][n] = s[r];
  } else if (w == 1) {
    f4 s = red2[0][l] + red2[1][l] + red2[2][l] + red2[3][l];
#pragma unroll
    for (int r = 0; r < 4; ++r) sbs[q * 4 + r][n] = s[r];
  } else if (w == 2) {
    ws1[l] = CS[l];
  } else {
    ws2[l] = CS[64 + l];
  }
  __syncthreads();
  if (tid < 192) {
    int rr = tid / 12, tt = tid - rr * 12;
    float irs = 1.f / fmaxf(sfs[rr][12], 1e-6f);
    float ics = 1.f / fmaxf(sbs[rr][12], 1e-6f);
    ccs[rr][tt] = 3.0f * (0.3f * sfs[rr][tt] * irs + 0.7f * sbs[rr][tt] * ics);
  }
  __syncthreads();

  // ================= Phase C: fused MLP ====================================
  // z A-frag regen: row = r0+n, k = c0*32 + q*8 + j
  auto zregen = [&](int c0) -> bf8 {
    int t = c0 >> 1, h0 = (c0 & 1) * 32 + q * 8;
    float xv = xs[n][t], cv = ccs[n][t];
    union { bf8 v; ush uu[8]; } au;
#pragma unroll
    for (int j = 0; j < 8; ++j)
      au.uu[j] = f2bu(fmaxf(fmaf(xv, ws1[h0 + j], cv * ws2[h0 + j]), 0.f));
    return au.v;
  };
  auto fpos = [&](int ct, int r) -> int {
    return ((ct >> 1) * 64 + ((ct & 1) * 2 + (n >> 3)) * 16 + q * 4 + r) * 8 + (n & 7);
  };

  // fill the z-frag cache (aliases T; all T reads are done): wave w owns 6 c0s
#pragma unroll
  for (int u6 = 0; u6 < 6; ++u6) {
    int c0 = w * 6 + u6;
    bf8 v = zregen(c0);
    *(bf8*)(&u.zf[((size_t)c0 * 64 + l) * 8]) = v;
  }
  __syncthreads();

  // --- L1e: h1 = relu(z @ ew1 + b1), N=128, wave does ct = 2w, 2w+1 --------
  {
    f4 a0 = {0.f, 0.f, 0.f, 0.f}, a1 = {0.f, 0.f, 0.f, 0.f};
    for (int c0 = 0; c0 < 24; ++c0) {
      bf8 a = *(const bf8*)(&u.zf[((size_t)c0 * 64 + l) * 8]);
      const ush* wb = Wf + ((size_t)(c0 * 8 + 2 * w) * 64 + l) * 8;
      bf8 b0 = *(const bf8*)wb;
      bf8 b1 = *(const bf8*)(wb + 512);
      a0 = __builtin_amdgcn_mfma_f32_16x16x32_bf16(a, b0, a0, 0, 0, 0);
      a1 = __builtin_amdgcn_mfma_f32_16x16x32_bf16(a, b1, a1, 0, 0, 0);
    }
#pragma unroll
    for (int u2 = 0; u2 < 2; ++u2) {
      int ct = 2 * w + u2;
      f4 acc = u2 ? a1 : a0;
      float bz = CS[128 + ct * 16 + n];
#pragma unroll
      for (int r = 0; r < 4; ++r)
        hf[fpos(ct, r)] = f2bu(fmaxf(acc[r] + bz, 0.f));
    }
  }
  __syncthreads();

  // --- L2e: h2 = relu(h1 @ ew2 + b2), K=128 --------------------------------
  {
    f4 a0 = {0.f, 0.f, 0.f, 0.f}, a1 = {0.f, 0.f, 0.f, 0.f};
    for (int c0 = 0; c0 < 4; ++c0) {
      bf8 a = *(const bf8*)(&hf[(size_t)(c0 * 64 + l) * 8]);
      const ush* wb = Wf + 98304 + ((size_t)(c0 * 8 + 2 * w) * 64 + l) * 8;
      bf8 b0 = *(const bf8*)wb;
      bf8 b1 = *(const bf8*)(wb + 512);
      a0 = __builtin_amdgcn_mfma_f32_16x16x32_bf16(a, b0, a0, 0, 0, 0);
      a1 = __builtin_amdgcn_mfma_f32_16x16x32_bf16(a, b1, a1, 0, 0, 0);
    }
    __syncthreads();   // hf reads complete before later rewrite
#pragma unroll
    for (int u2 = 0; u2 < 2; ++u2) {
      int ct = 2 * w + u2;
      f4 acc = u2 ? a1 : a0;
      float bz = CS[256 + ct * 16 + n];
#pragma unroll
      for (int r = 0; r < 4; ++r)
        hg[fpos(ct, r)] = f2bu(fmaxf(acc[r] + bz, 0.f));
    }
  }
  __syncthreads();

  // --- L3e: xe = BN(h2 @ ew3 + b3 + z @ eproj), N=64, wave does ct = w -----
  {
    f4 a3 = {0.f, 0.f, 0.f, 0.f};
    for (int c0 = 0; c0 < 4; ++c0) {
      bf8 a = *(const bf8*)(&hg[(size_t)(c0 * 64 + l) * 8]);
      bf8 bb = *(const bf8*)(Wf + 114688 + ((size_t)(c0 * 4 + w) * 64 + l) * 8);
      a3 = __builtin_amdgcn_mfma_f32_16x16x32_bf16(a, bb, a3, 0, 0, 0);
    }
    for (int c0 = 0; c0 < 24; ++c0) {
      bf8 a = *(const bf8*)(&u.zf[((size_t)c0 * 64 + l) * 8]);
      bf8 bb = *(const bf8*)(Wf + 122880 + ((size_t)(c0 * 4 + w) * 64 + l) * 8);
      a3 = __builtin_amdgcn_mfma_f32_16x16x32_bf16(a, bb, a3, 0, 0, 0);
    }
    int col = w * 16 + n;
    float g = CS[448 + col], be = CS[512 + col], mm = CS[576 + col], vv = CS[640 + col];
    float sc = g / sqrtf(vv + 1e-5f);
    float sh = be - mm * sc;
    float bz = CS[384 + col];
#pragma unroll
    for (int r = 0; r < 4; ++r)
      xf[fpos(w, r)] = f2bu((a3[r] + bz) * sc + sh);
  }
  __syncthreads();

  // --- L1d: g1 = relu(xe @ dw1 + b1), K=64, N=128 --------------------------
  {
    f4 a0 = {0.f, 0.f, 0.f, 0.f}, a1 = {0.f, 0.f, 0.f, 0.f};
    for (int c0 = 0; c0 < 2; ++c0) {
      bf8 a = *(const bf8*)(&xf[(size_t)(c0 * 64 + l) * 8]);
      const ush* wb = Wf + 172032 + ((size_t)(c0 * 8 + 2 * w) * 64 + l) * 8;
      bf8 b0 = *(const bf8*)wb;
      bf8 b1 = *(const bf8*)(wb + 512);
      a0 = __builtin_amdgcn_mfma_f32_16x16x32_bf16(a, b0, a0, 0, 0, 0);
      a1 = __builtin_amdgcn_mfma_f32_16x16x32_bf16(a, b1, a1, 0, 0, 0);
    }
    __syncthreads();   // hf rewrite fence
#pragma unroll
    for (int u2 = 0; u2 < 2; ++u2) {
      int ct = 2 * w + u2;
      f4 acc = u2 ? a1 : a0;
      float bz = CS[704 + ct * 16 + n];
#pragma unroll
      for (int r = 0; r < 4; ++r)
        hf[fpos(ct, r)] = f2bu(fmaxf(acc[r] + bz, 0.f));
    }
  }
  __syncthreads();

  // --- L2d: g2 = relu(g1 @ dw2 + b2), K=128 --------------------------------
  {
    f4 a0 = {0.f, 0.f, 0.f, 0.f}, a1 = {0.f, 0.f, 0.f, 0.f};
    for (int c0 = 0; c0 < 4; ++c0) {
      bf8 a = *(const bf8*)(&hf[(size_t)(c0 * 64 + l) * 8]);
      const ush* wb = Wf + 180224 + ((size_t)(c0 * 8 + 2 * w) * 64 + l) * 8;
      bf8 b0 = *(const bf8*)wb;
      bf8 b1 = *(const bf8*)(wb + 512);
      a0 = __builtin_amdgcn_mfma_f32_16x16x32_bf16(a, b0, a0, 0, 0, 0);
      a1 = __builtin_amdgcn_mfma_f32_16x16x32_bf16(a, b1, a1, 0, 0, 0);
    }
    __syncthreads();   // hg rewrite fence
#pragma unroll
    for (int u2 = 0; u2 < 2; ++u2) {
      int ct = 2 * w + u2;
      f4 acc = u2 ? a1 : a0;
      float bz = CS[832 + ct * 16 + n];
#pragma unroll
      for (int r = 0; r < 4; ++r)
        hg[fpos(ct, r)] = f2bu(fmaxf(acc[r] + bz, 0.f));
    }
  }
  __syncthreads();

  // --- L3d: out = BN(g2 @ dw3 + b3 + xe @ dproj), N=12; K-split 4 waves ----
  {
    f4 ao = {0.f, 0.f, 0.f, 0.f};
    {  // dw3 chunk c0 = w  (K=128 -> 4 chunks)
      bf8 a = *(const bf8*)(&hg[(size_t)(w * 64 + l) * 8]);
      bf8 bb = *(const bf8*)(Wf + 196608 + ((size_t)w * 64 + l) * 8);
      ao = __builtin_amdgcn_mfma_f32_16x16x32_bf16(a, bb, ao, 0, 0, 0);
    }
    if (w < 2) {  // dproj chunk c0 = w  (K=64 -> 2 chunks)
      bf8 a = *(const bf8*)(&xf[(size_t)(w * 64 + l) * 8]);
      bf8 bb = *(const bf8*)(Wf + 198656 + ((size_t)w * 64 + l) * 8);
      ao = __builtin_amdgcn_mfma_f32_16x16x32_bf16(a, bb, ao, 0, 0, 0);
    }
    red[w][l] = ao;
  }
  __syncthreads();
  if (w == 0) {
    f4 s = red[0][l] + red[1][l] + red[2][l] + red[3][l];
    int fl = flag[0];
    if (n < 12) {
      float bz = CS[960 + n];
      float g = CS[972 + n], be = CS[984 + n], mm = CS[996 + n], vv = CS[1008 + n];
      float sc = g / sqrtf(vv + 1e-5f);
      float sh = be - mm * sc;
#pragma unroll
      for (int r = 0; r < 4; ++r) {
        int row = r0 + q * 4 + r;
        int bb2 = row / Nn, nn2 = row - bb2 * Nn;
        size_t oi = ((size_t)bb2 * TOUT + n) * Nn + nn2;
        float ov = (s[r] + bz) * sc + sh;
        if (fl) ((float*)outp)[oi] = ov;
        else    ((ush*)outp)[oi] = f2bu(ov);
      }
    }
  }
}

}  // namespace

extern "C" void kernel_launch(void* const* d_in, const int* in_sizes, int n_in,
                              void* d_out, int out_size, void* d_ws, size_t ws_size,
                              hipStream_t stream) {
  float* f = (float*)d_ws;
  int* flag = (int*)d_ws;                 // f[0..15]
  float* CS  = f + 16;                    // 1020 small params (f32)
  float* xT  = f + 1040;                  // 147456
  float* sd  = f + 148496;                // 12288
  ush* U = (ush*)(f + 160784);
  ush* pA    = U;                         // 12288*32
  ush* lA    = U + 393216;
  ush* phi16 = U + 786432;                // 12288*16
  ush* plo16 = U + 983040;
  ush* lhi16 = U + 1179648;
  ush* llo16 = U + 1376256;
  ush* Xc    = U + 1572864;               // 8*16*1536
  ush* Wf    = U + 1769472;               // 199680

  SmallTab st;
  {
    const int idxs[16] = {1, 2, 4, 6, 8, 10, 11, 12, 13, 15, 17, 19, 21, 22, 23, 24};
    const int ns[16]   = {64, 64, 128, 128, 64, 64, 64, 64, 64, 128, 128, 12, 12, 12, 12, 12};
    int off = 0;
    for (int i = 0; i < 16; ++i) {
      st.src[i] = d_in[idxs[i]]; st.n[i] = ns[i]; st.off[i] = off; off += ns[i];
    }
  }
  RepTab rt;
  {
    const int idxs[8]  = {3, 5, 7, 9, 14, 16, 18, 20};
    const int rNc[8]   = {128, 128, 64, 64, 128, 128, 12, 12};
    const int rNCT[8]  = {8, 8, 4, 4, 8, 8, 1, 1};
    const int rlb[9]   = {0, 12288, 14336, 15360, 21504, 22528, 24576, 24832, 24960};
    for (int i = 0; i < 8; ++i) {
      rt.src[i] = d_in[idxs[i]]; rt.Nc[i] = rNc[i]; rt.NCT[i] = rNCT[i];
    }
    for (int i = 0; i < 9; ++i) rt.lb[i] = rlb[i];
  }

  prep_all<<<147, 256, 0, stream>>>(d_in[0], st, rt, flag, CS, xT, sd,
                                    pA, lA, phi16, plo16, lhi16, llo16, Xc, Wf);
  klmlp<<<768, 256, 0, stream>>>(xT, pA, lA, phi16, plo16, lhi16, llo16,
                                 Xc, sd, CS, Wf, flag, d_out);
}

// Round 4
// 139.291 us; speedup vs baseline: 1.4316x; 1.0227x over previous
//
#include <hip/hip_runtime.h>
#include <hip/hip_bf16.h>

// AdaBiD R10: 2-kernel pipeline. MI355X gfx950.
// B=8, T=12, N=1536, H=64, TH=768, HID2=128, T_OUT=12.
//  K1 prep_all: [0,192) softmax/logp/self-dot, 4 THREADS PER ROW (64 rows/blk)
//               -- 4x the parallelism of R9's 48-block role; exp/Z chain
//               computed redundantly per sub-lane (bit-identical order),
//               logf/splits/stores split 3-per-sub, sacc via LDS+fmaf chain.
//               [192,290) weight repack -> B-frag order, 290 smalls + flag.
//  K2 klmlp: fused KL + 6-layer MLP per 16-row tile (768 blocks), unchanged
//               from R9 except: A-frags read directly from phi/plo/lhi/llo
//               (pA/lA arrays deleted) and xs read directly from x input
//               (xT array deleted).

namespace {

constexpr int Nn = 1536, TOUT = 12;

typedef __attribute__((ext_vector_type(8))) short bf8;
typedef __attribute__((ext_vector_type(4))) float f4;
typedef unsigned short ush;

__device__ __forceinline__ float b2f(__hip_bfloat16 v) { return __bfloat162float(v); }
__device__ __forceinline__ ush f2bu(float f) {
  union { __hip_bfloat16 h; ush u; } c; c.h = __float2bfloat16(f); return c.u;
}
__device__ __forceinline__ float bu2f(ush u) {
  union { unsigned int i; float f; } c; c.i = ((unsigned)u) << 16; return c.f;
}
__device__ __forceinline__ float ldraw(const void* p, size_t i, int fl) {
  return fl ? ((const float*)p)[i] : b2f(((const __hip_bfloat16*)p)[i]);
}

// block-local dtype sniff: bf16 N(0,1) never has exp-field >= 140; f32 read
// as ushorts has ~45% of low-halves >= 140.  4096 samples.
__device__ __forceinline__ int detect_fl(const void* x, int tid) {
  __shared__ int cnt;
  if (tid == 0) cnt = 0;
  __syncthreads();
  const ush* u = (const ush*)x;
  int c = 0;
#pragma unroll
  for (int s = 0; s < 16; ++s) {
    ush v = u[tid + s * 256];
    if (((v >> 7) & 0xFF) >= 140) c++;
  }
  atomicAdd(&cnt, c);
  __syncthreads();
  return (cnt > 64) ? 1 : 0;
}

struct SmallTab { const void* src[16]; int n[16]; int off[16]; };
struct RepTab { const void* src[8]; int Nc[8]; int NCT[8]; int lb[9]; };

// ---------------- K1: prep + repack + smalls ---------------------------------
__global__ __launch_bounds__(256) void prep_all(
    const void* __restrict__ xraw, SmallTab st, RepTab rt,
    int* __restrict__ flag, float* __restrict__ CS,
    float* __restrict__ sd,
    ush* __restrict__ phi16, ush* __restrict__ plo16,
    ush* __restrict__ lhi16, ush* __restrict__ llo16,
    ush* __restrict__ Xc, ush* __restrict__ Wf) {
  __shared__ float lvs[64][12];
  int tid = threadIdx.x;
  int fl = detect_fl(xraw, tid);
  int blk = blockIdx.x;

  if (blk < 192) {
    // ---- prep role: 64 rows/block, 4 threads per row ----
    int rl = tid >> 2, sub = tid & 3;
    int row = blk * 64 + rl;
    int b = row / Nn, nn = row - b * Nn;   // 24 blocks/batch, no straddle
    float xv[12];
#pragma unroll
    for (int t = 0; t < 12; ++t)
      xv[t] = ldraw(xraw, (size_t)(b * 12 + t) * Nn + nn, fl);
    // redundant per-sub, bit-identical sequential order
    float mx = xv[0];
#pragma unroll
    for (int t = 1; t < 12; ++t) mx = fmaxf(mx, xv[t]);
    float e[12], Z = 0.f;
#pragma unroll
    for (int t = 0; t < 12; ++t) { e[t] = expf(xv[t] - mx); Z += e[t]; }
    float invZ = 1.f / Z;
    // each sub owns t = sub*3 .. sub*3+2: log + splits + stores
#pragma unroll
    for (int u = 0; u < 3; ++u) {
      int t = sub * 3 + u;
      float pv = e[t] * invZ;
      float lv = logf(pv + 1e-10f);
      lvs[rl][t] = lv;
      ush phv = f2bu(pv);  float plv = pv - bu2f(phv);
      ush lhv = f2bu(lv);  float llv = lv - bu2f(lhv);
      phi16[(size_t)row * 16 + t] = phv;
      plo16[(size_t)row * 16 + t] = f2bu(plv);
      lhi16[(size_t)row * 16 + t] = lhv;
      llo16[(size_t)row * 16 + t] = f2bu(llv);
      Xc[((size_t)(b * 16 + t)) * Nn + nn] = f2bu(xv[t]);
    }
    {  // pads: t = 12+sub for all arrays; Xc ones col at t=12
      int t = 12 + sub;
      phi16[(size_t)row * 16 + t] = 0;
      plo16[(size_t)row * 16 + t] = 0;
      lhi16[(size_t)row * 16 + t] = 0;
      llo16[(size_t)row * 16 + t] = 0;
      Xc[((size_t)(b * 16 + t)) * Nn + nn] = (sub == 0) ? (ush)0x3F80 : (ush)0;
    }
    __syncthreads();
    if (sub == 0) {
      float sacc = 0.f;
#pragma unroll
      for (int t = 0; t < 12; ++t)
        sacc = fmaf(e[t] * invZ, lvs[rl][t], sacc);
      sd[row] = sacc;
    }
  } else if (blk < 290) {
    // ---- repack role: weights -> MFMA B-frag order ----
    int idx = (blk - 192) * 256 + tid;
    if (idx >= rt.lb[8]) return;
    int mi = 0;
#pragma unroll
    for (int i = 1; i < 8; ++i) if (idx >= rt.lb[i]) mi = i;
    int li = idx - rt.lb[mi];
    int NCT = rt.NCT[mi], Nc = rt.Nc[mi];
    int per = NCT * 64;
    int c0 = li / per, rem = li - c0 * per;
    int ct = rem >> 6, l = rem & 63;
    int q = l >> 4, m = l & 15;
    int col = ct * 16 + m;
    ush* d = Wf + (size_t)idx * 8;
#pragma unroll
    for (int j = 0; j < 8; ++j) {
      int k = c0 * 32 + q * 8 + j;
      d[j] = (col < Nc) ? f2bu(ldraw(rt.src[mi], (size_t)k * Nc + col, fl)) : 0;
    }
  } else {
    // ---- smalls role: canonicalize biases/BN params to f32 + publish flag ----
    for (int i = 0; i < 16; ++i)
      for (int e = tid; e < st.n[i]; e += 256)
        CS[st.off[i] + e] = ldraw(st.src[i], e, fl);
    if (tid == 0) flag[0] = fl;
  }
}

// ---------------- K2: fused KL + MLP per 16-row tile -------------------------
__global__ __launch_bounds__(256, 3) void klmlp(
    const void* __restrict__ xraw,
    const ush* __restrict__ phi16, const ush* __restrict__ plo16,
    const ush* __restrict__ lhi16, const ush* __restrict__ llo16,
    const ush* __restrict__ Xc, const float* __restrict__ sd,
    const float* __restrict__ CS, const ush* __restrict__ Wf,
    const int* __restrict__ flag, void* __restrict__ outp) {
  __shared__ float xs[16][12], ccs[16][12];
  __shared__ float sfs[16][16], sbs[16][16];
  __shared__ float ws1[64], ws2[64];
  __shared__ ush hf[2048], hg[2048], xf[1024];
  __shared__ f4 red[4][64], red2[4][64];
  __shared__ union { ush T[2][4][512]; ush zf[12288]; } u;   // 24 KB alias

  int tid = threadIdx.x, w = tid >> 6, l = tid & 63, q = l >> 4, n = l & 15;
  int bi = blockIdx.x;
  int r0 = bi * 16;
  int b = bi / 96;            // 96 blocks per batch (1536/16)
  int rowb = b * Nn;
  int fl = flag[0];

  // xs staging overlaps phase B (independent loads)
  if (tid < 192) {
    int rr = tid / 12, tt = tid - rr * 12;
    xs[rr][tt] = ldraw(xraw, (size_t)(b * 12 + tt) * Nn + (r0 - rowb + rr), fl);
  }

  // ================= Phase B: KL + aggregation, 4 waves split j =============
  {
    bf8 z8 = {0, 0, 0, 0, 0, 0, 0, 0};
    // A-frags straight from the hi/lo row arrays: k<16 -> hi, k>=16 -> lo
    bf8 aP = (q < 2)
        ? *(const bf8*)(phi16 + ((size_t)(r0 + n)) * 16 + q * 8)
        : *(const bf8*)(plo16 + ((size_t)(r0 + n)) * 16 + (q - 2) * 8);
    bf8 aL = (q < 2)
        ? *(const bf8*)(lhi16 + ((size_t)(r0 + n)) * 16 + q * 8)
        : *(const bf8*)(llo16 + ((size_t)(r0 + n)) * 16 + (q - 2) * 8);
    bf8 aPh = (q < 2) ? aP : z8;
    bf8 aLh = (q < 2) ? aL : z8;
    float selfI[4];
#pragma unroll
    for (int r = 0; r < 4; ++r) selfI[r] = sd[r0 + q * 4 + r];

    f4 accF = {0.f, 0.f, 0.f, 0.f}, accB = {0.f, 0.f, 0.f, 0.f};

    for (int jp = 0; jp < 12; ++jp) {
      int jl = w * 384 + jp * 32;
#pragma unroll
      for (int hh = 0; hh < 2; ++hh) {
        int jh = jl + hh * 16;
        size_t bb = ((size_t)(rowb + jh + n)) * 16 + (q & 1) * 8;
        bf8 bLh = *(const bf8*)(lhi16 + bb);
        bf8 bLo = *(const bf8*)(llo16 + bb);
        bf8 bPh = *(const bf8*)(phi16 + bb);
        bf8 bPo = *(const bf8*)(plo16 + bb);
        float selfJ = sd[rowb + jh + n];

        f4 s1 = {0.f, 0.f, 0.f, 0.f}, s2 = {0.f, 0.f, 0.f, 0.f};
        s1 = __builtin_amdgcn_mfma_f32_16x16x32_bf16(aP, bLh, s1, 0, 0, 0);
        s1 = __builtin_amdgcn_mfma_f32_16x16x32_bf16(aPh, bLo, s1, 0, 0, 0);
        s2 = __builtin_amdgcn_mfma_f32_16x16x32_bf16(aL, bPh, s2, 0, 0, 0);
        s2 = __builtin_amdgcn_mfma_f32_16x16x32_bf16(aLh, bPo, s2, 0, 0, 0);

        int qk = n >> 3, kj = n & 7;
#pragma unroll
        for (int r = 0; r < 4; ++r) {
          int pos = hh * 256 + (qk * 16 + q * 4 + r) * 8 + kj;
          u.T[0][w][pos] = (selfI[r] - s1[r] < 0.5f) ? (ush)0x3F80 : (ush)0;
          u.T[1][w][pos] = (selfJ - s2[r] < 0.5f) ? (ush)0x3F80 : (ush)0;
        }
      }
      bf8 af1 = *(const bf8*)(&u.T[0][w][(size_t)l * 8]);
      bf8 af2 = *(const bf8*)(&u.T[1][w][(size_t)l * 8]);
      bf8 xfr = *(const bf8*)(Xc + ((size_t)(b * 16 + n)) * Nn + jl + q * 8);
      accF = __builtin_amdgcn_mfma_f32_16x16x32_bf16(af1, xfr, accF, 0, 0, 0);
      accB = __builtin_amdgcn_mfma_f32_16x16x32_bf16(af2, xfr, accB, 0, 0, 0);
    }
    red[w][l] = accF;
    red2[w][l] = accB;
  }
  __syncthreads();

  // j-split reduction -> sfs/sbs; waves 2,3 stage W1/W2 meanwhile
  if (w == 0) {
    f4 s = red[0][l] + red[1][l] + red[2][l] + red[3][l];
#pragma unroll
    for (int r = 0; r < 4; ++r) sfs[q * 4 + r][n] = s[r];
  } else if (w == 1) {
    f4 s = red2[0][l] + red2[1][l] + red2[2][l] + red2[3][l];
#pragma unroll
    for (int r = 0; r < 4; ++r) sbs[q * 4 + r][n] = s[r];
  } else if (w == 2) {
    ws1[l] = CS[l];
  } else {
    ws2[l] = CS[64 + l];
  }
  __syncthreads();
  if (tid < 192) {
    int rr = tid / 12, tt = tid - rr * 12;
    float irs = 1.f / fmaxf(sfs[rr][12], 1e-6f);
    float ics = 1.f / fmaxf(sbs[rr][12], 1e-6f);
    ccs[rr][tt] = 3.0f * (0.3f * sfs[rr][tt] * irs + 0.7f * sbs[rr][tt] * ics);
  }
  __syncthreads();

  // ================= Phase C: fused MLP ====================================
  // z A-frag regen: row = r0+n, k = c0*32 + q*8 + j
  auto zregen = [&](int c0) -> bf8 {
    int t = c0 >> 1, h0 = (c0 & 1) * 32 + q * 8;
    float xv = xs[n][t], cv = ccs[n][t];
    union { bf8 v; ush uu[8]; } au;
#pragma unroll
    for (int j = 0; j < 8; ++j)
      au.uu[j] = f2bu(fmaxf(fmaf(xv, ws1[h0 + j], cv * ws2[h0 + j]), 0.f));
    return au.v;
  };
  auto fpos = [&](int ct, int r) -> int {
    return ((ct >> 1) * 64 + ((ct & 1) * 2 + (n >> 3)) * 16 + q * 4 + r) * 8 + (n & 7);
  };

  // fill the z-frag cache (aliases T; all T reads are done): wave w owns 6 c0s
#pragma unroll
  for (int u6 = 0; u6 < 6; ++u6) {
    int c0 = w * 6 + u6;
    bf8 v = zregen(c0);
    *(bf8*)(&u.zf[((size_t)c0 * 64 + l) * 8]) = v;
  }
  __syncthreads();

  // --- L1e: h1 = relu(z @ ew1 + b1), N=128, wave does ct = 2w, 2w+1 --------
  {
    f4 a0 = {0.f, 0.f, 0.f, 0.f}, a1 = {0.f, 0.f, 0.f, 0.f};
    for (int c0 = 0; c0 < 24; ++c0) {
      bf8 a = *(const bf8*)(&u.zf[((size_t)c0 * 64 + l) * 8]);
      const ush* wb = Wf + ((size_t)(c0 * 8 + 2 * w) * 64 + l) * 8;
      bf8 b0 = *(const bf8*)wb;
      bf8 b1 = *(const bf8*)(wb + 512);
      a0 = __builtin_amdgcn_mfma_f32_16x16x32_bf16(a, b0, a0, 0, 0, 0);
      a1 = __builtin_amdgcn_mfma_f32_16x16x32_bf16(a, b1, a1, 0, 0, 0);
    }
#pragma unroll
    for (int u2 = 0; u2 < 2; ++u2) {
      int ct = 2 * w + u2;
      f4 acc = u2 ? a1 : a0;
      float bz = CS[128 + ct * 16 + n];
#pragma unroll
      for (int r = 0; r < 4; ++r)
        hf[fpos(ct, r)] = f2bu(fmaxf(acc[r] + bz, 0.f));
    }
  }
  __syncthreads();

  // --- L2e: h2 = relu(h1 @ ew2 + b2), K=128 --------------------------------
  {
    f4 a0 = {0.f, 0.f, 0.f, 0.f}, a1 = {0.f, 0.f, 0.f, 0.f};
    for (int c0 = 0; c0 < 4; ++c0) {
      bf8 a = *(const bf8*)(&hf[(size_t)(c0 * 64 + l) * 8]);
      const ush* wb = Wf + 98304 + ((size_t)(c0 * 8 + 2 * w) * 64 + l) * 8;
      bf8 b0 = *(const bf8*)wb;
      bf8 b1 = *(const bf8*)(wb + 512);
      a0 = __builtin_amdgcn_mfma_f32_16x16x32_bf16(a, b0, a0, 0, 0, 0);
      a1 = __builtin_amdgcn_mfma_f32_16x16x32_bf16(a, b1, a1, 0, 0, 0);
    }
    __syncthreads();   // hf reads complete before later rewrite
#pragma unroll
    for (int u2 = 0; u2 < 2; ++u2) {
      int ct = 2 * w + u2;
      f4 acc = u2 ? a1 : a0;
      float bz = CS[256 + ct * 16 + n];
#pragma unroll
      for (int r = 0; r < 4; ++r)
        hg[fpos(ct, r)] = f2bu(fmaxf(acc[r] + bz, 0.f));
    }
  }
  __syncthreads();

  // --- L3e: xe = BN(h2 @ ew3 + b3 + z @ eproj), N=64, wave does ct = w -----
  {
    f4 a3 = {0.f, 0.f, 0.f, 0.f};
    for (int c0 = 0; c0 < 4; ++c0) {
      bf8 a = *(const bf8*)(&hg[(size_t)(c0 * 64 + l) * 8]);
      bf8 bb = *(const bf8*)(Wf + 114688 + ((size_t)(c0 * 4 + w) * 64 + l) * 8);
      a3 = __builtin_amdgcn_mfma_f32_16x16x32_bf16(a, bb, a3, 0, 0, 0);
    }
    for (int c0 = 0; c0 < 24; ++c0) {
      bf8 a = *(const bf8*)(&u.zf[((size_t)c0 * 64 + l) * 8]);
      bf8 bb = *(const bf8*)(Wf + 122880 + ((size_t)(c0 * 4 + w) * 64 + l) * 8);
      a3 = __builtin_amdgcn_mfma_f32_16x16x32_bf16(a, bb, a3, 0, 0, 0);
    }
    int col = w * 16 + n;
    float g = CS[448 + col], be = CS[512 + col], mm = CS[576 + col], vv = CS[640 + col];
    float sc = g / sqrtf(vv + 1e-5f);
    float sh = be - mm * sc;
    float bz = CS[384 + col];
#pragma unroll
    for (int r = 0; r < 4; ++r)
      xf[fpos(w, r)] = f2bu((a3[r] + bz) * sc + sh);
  }
  __syncthreads();

  // --- L1d: g1 = relu(xe @ dw1 + b1), K=64, N=128 --------------------------
  {
    f4 a0 = {0.f, 0.f, 0.f, 0.f}, a1 = {0.f, 0.f, 0.f, 0.f};
    for (int c0 = 0; c0 < 2; ++c0) {
      bf8 a = *(const bf8*)(&xf[(size_t)(c0 * 64 + l) * 8]);
      const ush* wb = Wf + 172032 + ((size_t)(c0 * 8 + 2 * w) * 64 + l) * 8;
      bf8 b0 = *(const bf8*)wb;
      bf8 b1 = *(const bf8*)(wb + 512);
      a0 = __builtin_amdgcn_mfma_f32_16x16x32_bf16(a, b0, a0, 0, 0, 0);
      a1 = __builtin_amdgcn_mfma_f32_16x16x32_bf16(a, b1, a1, 0, 0, 0);
    }
    __syncthreads();   // hf rewrite fence
#pragma unroll
    for (int u2 = 0; u2 < 2; ++u2) {
      int ct = 2 * w + u2;
      f4 acc = u2 ? a1 : a0;
      float bz = CS[704 + ct * 16 + n];
#pragma unroll
      for (int r = 0; r < 4; ++r)
        hf[fpos(ct, r)] = f2bu(fmaxf(acc[r] + bz, 0.f));
    }
  }
  __syncthreads();

  // --- L2d: g2 = relu(g1 @ dw2 + b2), K=128 --------------------------------
  {
    f4 a0 = {0.f, 0.f, 0.f, 0.f}, a1 = {0.f, 0.f, 0.f, 0.f};
    for (int c0 = 0; c0 < 4; ++c0) {
      bf8 a = *(const bf8*)(&hf[(size_t)(c0 * 64 + l) * 8]);
      const ush* wb = Wf + 180224 + ((size_t)(c0 * 8 + 2 * w) * 64 + l) * 8;
      bf8 b0 = *(const bf8*)wb;
      bf8 b1 = *(const bf8*)(wb + 512);
      a0 = __builtin_amdgcn_mfma_f32_16x16x32_bf16(a, b0, a0, 0, 0, 0);
      a1 = __builtin_amdgcn_mfma_f32_16x16x32_bf16(a, b1, a1, 0, 0, 0);
    }
    __syncthreads();   // hg rewrite fence
#pragma unroll
    for (int u2 = 0; u2 < 2; ++u2) {
      int ct = 2 * w + u2;
      f4 acc = u2 ? a1 : a0;
      float bz = CS[832 + ct * 16 + n];
#pragma unroll
      for (int r = 0; r < 4; ++r)
        hg[fpos(ct, r)] = f2bu(fmaxf(acc[r] + bz, 0.f));
    }
  }
  __syncthreads();

  // --- L3d: out = BN(g2 @ dw3 + b3 + xe @ dproj), N=12; K-split 4 waves ----
  {
    f4 ao = {0.f, 0.f, 0.f, 0.f};
    {  // dw3 chunk c0 = w  (K=128 -> 4 chunks)
      bf8 a = *(const bf8*)(&hg[(size_t)(w * 64 + l) * 8]);
      bf8 bb = *(const bf8*)(Wf + 196608 + ((size_t)w * 64 + l) * 8);
      ao = __builtin_amdgcn_mfma_f32_16x16x32_bf16(a, bb, ao, 0, 0, 0);
    }
    if (w < 2) {  // dproj chunk c0 = w  (K=64 -> 2 chunks)
      bf8 a = *(const bf8*)(&xf[(size_t)(w * 64 + l) * 8]);
      bf8 bb = *(const bf8*)(Wf + 198656 + ((size_t)w * 64 + l) * 8);
      ao = __builtin_amdgcn_mfma_f32_16x16x32_bf16(a, bb, ao, 0, 0, 0);
    }
    red[w][l] = ao;
  }
  __syncthreads();
  if (w == 0) {
    f4 s = red[0][l] + red[1][l] + red[2][l] + red[3][l];
    if (n < 12) {
      float bz = CS[960 + n];
      float g = CS[972 + n], be = CS[984 + n], mm = CS[996 + n], vv = CS[1008 + n];
      float sc = g / sqrtf(vv + 1e-5f);
      float sh = be - mm * sc;
#pragma unroll
      for (int r = 0; r < 4; ++r) {
        int row = r0 + q * 4 + r;
        int bb2 = row / Nn, nn2 = row - bb2 * Nn;
        size_t oi = ((size_t)bb2 * TOUT + n) * Nn + nn2;
        float ov = (s[r] + bz) * sc + sh;
        if (fl) ((float*)outp)[oi] = ov;
        else    ((ush*)outp)[oi] = f2bu(ov);
      }
    }
  }
}

}  // namespace

extern "C" void kernel_launch(void* const* d_in, const int* in_sizes, int n_in,
                              void* d_out, int out_size, void* d_ws, size_t ws_size,
                              hipStream_t stream) {
  float* f = (float*)d_ws;
  int* flag = (int*)d_ws;                 // f[0..15]
  float* CS  = f + 16;                    // 1020 small params (f32)
  float* sd  = f + 1040;                  // 12288
  ush* U = (ush*)(f + 13328);
  ush* phi16 = U;                         // 12288*16
  ush* plo16 = U + 196608;
  ush* lhi16 = U + 393216;
  ush* llo16 = U + 589824;
  ush* Xc    = U + 786432;                // 8*16*1536
  ush* Wf    = U + 983040;                // 199680

  SmallTab st;
  {
    const int idxs[16] = {1, 2, 4, 6, 8, 10, 11, 12, 13, 15, 17, 19, 21, 22, 23, 24};
    const int ns[16]   = {64, 64, 128, 128, 64, 64, 64, 64, 64, 128, 128, 12, 12, 12, 12, 12};
    int off = 0;
    for (int i = 0; i < 16; ++i) {
      st.src[i] = d_in[idxs[i]]; st.n[i] = ns[i]; st.off[i] = off; off += ns[i];
    }
  }
  RepTab rt;
  {
    const int idxs[8]  = {3, 5, 7, 9, 14, 16, 18, 20};
    const int rNc[8]   = {128, 128, 64, 64, 128, 128, 12, 12};
    const int rNCT[8]  = {8, 8, 4, 4, 8, 8, 1, 1};
    const int rlb[9]   = {0, 12288, 14336, 15360, 21504, 22528, 24576, 24832, 24960};
    for (int i = 0; i < 8; ++i) {
      rt.src[i] = d_in[idxs[i]]; rt.Nc[i] = rNc[i]; rt.NCT[i] = rNCT[i];
    }
    for (int i = 0; i < 9; ++i) rt.lb[i] = rlb[i];
  }

  prep_all<<<291, 256, 0, stream>>>(d_in[0], st, rt, flag, CS, sd,
                                    phi16, plo16, lhi16, llo16, Xc, Wf);
  klmlp<<<768, 256, 0, stream>>>(d_in[0], phi16, plo16, lhi16, llo16,
                                 Xc, sd, CS, Wf, flag, d_out);
}